// Round 18
// baseline (233.311 us; speedup 1.0000x reference)
//
#include <hip/hip_runtime.h>
#include <hip/hip_bf16.h>

// ---------- constants ----------
#define B_   8
#define CIN  64
#define DIMS 64
#define NW   8
#define T_   16
#define H_   56
#define W_   56
#define HID  17
#define THW  (T_*H_*W_)          // 50176
#define HW   (H_*W_)             // 3136
#define NPC  401408              // B*T*H*W per channel
#define EPS  1e-5f
#define PROWS 348                // 6 h-rows * 58 w-cols per LDS slice

typedef __bf16 bf16x8 __attribute__((ext_vector_type(8)));
typedef float f32x4 __attribute__((ext_vector_type(4)));

// workspace offsets (bytes)
#define OFF_XT     0             // xT bf16 = 51,380,224 B
#define OFF_AT     51380224      // At2 = 1,769,472 B
#define OFF_POOLED 53149696      // 512 u32
#define OFF_CHSUM  53151744
#define OFF_CHSQ   53152000
#define OFF_PHI    53152256
#define OFF_DYNB   53152512
#define OFF_SCALE  53154560
#define OFF_SHIFT  53154816
#define OFF_Y      53155072      // optional bf16 y = 51,380,224 B (needs big ws)
#define WS_NEED_BF16Y (OFF_Y + 51380224)

__device__ __forceinline__ unsigned short f2bf(float f) {
    unsigned int u = __float_as_uint(f);
    u += 0x7fffu + ((u >> 16) & 1u);         // RNE (finite values)
    return (unsigned short)(u >> 16);
}
__device__ __forceinline__ float bf2f(unsigned short u) {
    return __uint_as_float(((unsigned int)u) << 16);
}
__device__ __forceinline__ unsigned int fenc(float f) {
    unsigned int b = __float_as_uint(f);
    return (b & 0x80000000u) ? ~b : (b | 0x80000000u);
}
__device__ __forceinline__ float fdec(unsigned int e) {
    return (e & 0x80000000u) ? __uint_as_float(e & 0x7fffffffu) : __uint_as_float(~e);
}

__device__ __forceinline__ float waveRedSum(float v) {
    #pragma unroll
    for (int o = 32; o > 0; o >>= 1) v += __shfl_down(v, o);
    return v;
}

// ---------- K0: transpose x -> xT[b][t][h][w][c] bf16, fused global max pool ----------
__global__ __launch_bounds__(256) void xpose_kernel(const float* __restrict__ x,
                                                    unsigned short* __restrict__ xT,
                                                    unsigned int* __restrict__ pooled_u) {
    __shared__ float tile[CIN * W_];         // 14,336 B
    const int h = blockIdx.x, t = blockIdx.y, b = blockIdx.z;
    const int tid = threadIdx.x;
    {   // read: lane = w (coalesced 224B per c-row)
        const int w = tid & 63, cg = tid >> 6;
        if (w < W_) {
            const size_t base = ((size_t)(b * CIN) * T_ + t) * HW + h * W_ + w;
            #pragma unroll
            for (int k = 0; k < 16; ++k) {
                const int c = cg * 16 + k;
                tile[c * W_ + w] = x[base + (size_t)c * (T_ * HW)];
            }
        }
    }
    __syncthreads();
    {   // write: 32B per thread, fully coalesced
        const int w = tid >> 2, cq = tid & 3;
        if (w < W_) {
            unsigned int pk[8];
            #pragma unroll
            for (int kk = 0; kk < 8; ++kk) {
                const float f0 = tile[(cq * 16 + kk * 2) * W_ + w];
                const float f1 = tile[(cq * 16 + kk * 2 + 1) * W_ + w];
                pk[kk] = (unsigned int)f2bf(f0) | ((unsigned int)f2bf(f1) << 16);
            }
            unsigned short* dst = xT + ((((size_t)b * T_ + t) * H_ + h) * W_ + w) * CIN + cq * 16;
            *reinterpret_cast<uint4*>(dst)     = make_uint4(pk[0], pk[1], pk[2], pk[3]);
            *reinterpret_cast<uint4*>(dst + 8) = make_uint4(pk[4], pk[5], pk[6], pk[7]);
        }
    }
    if (tid < CIN) {
        float m = -3.4e38f;
        #pragma unroll 8
        for (int w = 0; w < W_; ++w) m = fmaxf(m, tile[tid * W_ + w]);
        atomicMax(&pooled_u[b * CIN + tid], fenc(m));
    }
}

// ---------- K2: MLP -> softmax(phi) -> dyn_b ----------
__global__ __launch_bounds__(256) void mlp_kernel(const unsigned int* __restrict__ pooled_u,
                                                  const float* __restrict__ W1,
                                                  const float* __restrict__ b1,
                                                  const float* __restrict__ W2,
                                                  const float* __restrict__ b2,
                                                  const float* __restrict__ biases,
                                                  const void* __restrict__ epochs,
                                                  float* __restrict__ phi_out,
                                                  float* __restrict__ dynb) {
    __shared__ float pool_s[B_ * CIN];
    __shared__ float h_s[B_ * HID];
    __shared__ float lg_s[B_ * NW];
    __shared__ float phi_s[B_ * NW];
    const int tid = threadIdx.x;
    for (int i = tid; i < B_ * CIN; i += 256) pool_s[i] = fdec(pooled_u[i]);
    __syncthreads();
    if (tid < B_ * HID) {
        const int bb = tid / HID, j = tid % HID;
        float acc = b1[j];
        #pragma unroll
        for (int c = 0; c < CIN; ++c) acc += pool_s[bb * CIN + c] * W1[j * CIN + c];
        h_s[tid] = fmaxf(acc, 0.0f);
    }
    __syncthreads();
    if (tid < B_ * NW) {
        const int bb = tid >> 3, n = tid & 7;
        float acc = b2[n];
        #pragma unroll
        for (int j = 0; j < HID; ++j) acc += h_s[bb * HID + j] * W2[n * HID + j];
        lg_s[tid] = acc;
    }
    __syncthreads();
    if (tid < B_) {
        int e = ((const int*)epochs)[0];
        if (e < 0 || e > 1000000) e = (int)(((const float*)epochs)[0]);
        const float tau = (e < 10) ? (30.0f - 2.9f * (float)e) : 1.0f;
        float mx = -3.4e38f;
        #pragma unroll
        for (int n = 0; n < NW; ++n) mx = fmaxf(mx, lg_s[tid * NW + n]);
        float ex[NW], s = 0.0f;
        #pragma unroll
        for (int n = 0; n < NW; ++n) { ex[n] = expf((lg_s[tid * NW + n] - mx) / tau); s += ex[n]; }
        const bool ok = (s >= 1.0f) && (s < 1e37f);
        const float inv = ok ? (1.0f / s) : 0.0f;
        #pragma unroll
        for (int n = 0; n < NW; ++n) phi_s[tid * NW + n] = ok ? (ex[n] * inv) : 0.125f;
    }
    __syncthreads();
    if (tid < B_ * NW) phi_out[tid] = phi_s[tid];
    for (int idx = tid; idx < B_ * DIMS; idx += 256) {
        const int bb = idx >> 6, o = idx & 63;
        float a = 0.0f;
        #pragma unroll
        for (int n = 0; n < NW; ++n) a += phi_s[bb * NW + n] * biases[n * DIMS + o];
        dynb[idx] = a;
    }
}

// ---------- K3: synthesize At2 — coalesced reads (block = b x o-pair) ----------
__global__ __launch_bounds__(256) void awgen_kernel(const float* __restrict__ weights,
                                                    const float* __restrict__ phi,
                                                    unsigned short* __restrict__ At2) {
    const int b = blockIdx.x >> 5, oc = blockIdx.x & 31;  // 256 blocks
    const int o0 = oc * 2;
    __shared__ float ph[NW];
    if (threadIdx.x < NW) ph[threadIdx.x] = phi[b * NW + threadIdx.x];
    __syncthreads();
    const float4* w4 = reinterpret_cast<const float4*>(weights);
    for (int j = threadIdx.x; j < 864; j += 256) {
        f32x4 a = (f32x4){0.f, 0.f, 0.f, 0.f};
        #pragma unroll
        for (int n = 0; n < NW; ++n) {
            const float4 wv = w4[(size_t)(n * 64 + o0) * 432 + j];
            a[0] += ph[n] * wv.x;
            a[1] += ph[n] * wv.y;
            a[2] += ph[n] * wv.z;
            a[3] += ph[n] * wv.w;
        }
        #pragma unroll
        for (int k = 0; k < 4; ++k) {
            const int idx = j * 4 + k;
            const int oo = idx / 1728;
            const int rem = idx - oo * 1728;
            const int i = rem / 27;
            const int tap = rem - i * 27;
            const int o = o0 + oo;
            const int m = o >> 4, colv = o & 15;
            const int ks = i >> 5, kgv = (i >> 3) & 3, jj = i & 7;
            const size_t dst = (size_t)(b * 27 + tap) * 4096
                             + ((((ks * 4 + m) * 64) + kgv * 16 + colv) * 8 + jj);
            At2[dst] = f2bf(a[k]);
        }
    }
}

// ---------- K4: MFMA conv — XCD swizzle + whole-compute-phase setprio ----------
// r17's setprio covered only each 32-MFMA cluster (+22%). This round: raise
// priority for the ENTIRE 9-tap compute section (A-loads + B-reads + MFMA),
// keep staging/drain at prio 0 — compute-phase waves win arbitration end-to-end.
template<int BF16Y>
__global__ __launch_bounds__(256) void conv_kernel(const unsigned short* __restrict__ xT,
                                                   const unsigned short* __restrict__ At2,
                                                   const float* __restrict__ dynb,
                                                   float* __restrict__ yf,
                                                   unsigned short* __restrict__ yb) {
    __shared__ __align__(16) unsigned char xs[PROWS * 128];   // 44,544 B
    const int swz = (blockIdx.x & 7) * 224 + (blockIdx.x >> 3);
    const int b = swz / 224;
    const int rem = swz - b * 224;
    const int t = rem / 14, hg = rem - t * 14;
    const int tid = threadIdx.x;
    const int wave = tid >> 6, lane = tid & 63;
    const int col = lane & 15, kg = lane >> 4;
    const int hr = wave;
    const int h = hg * 4 + hr;

    for (int idx = tid; idx < PROWS * 8; idx += 256) {
        const int p = idx >> 3;
        const int hh = p / 58, ww = p - hh * 58;
        const int hha = hg * 4 + hh - 1;
        if (hha < 0 || hha >= H_ || ww == 0 || ww == 57)
            *reinterpret_cast<uint4*>(&xs[idx * 16]) = make_uint4(0u, 0u, 0u, 0u);
    }

    f32x4 acc[4][4];
    #pragma unroll
    for (int m = 0; m < 4; ++m)
        #pragma unroll
        for (int n = 0; n < 4; ++n) acc[m][n] = (f32x4){0.f, 0.f, 0.f, 0.f};

    const int sub = lane >> 3, q = lane & 7;

    for (int kd = 0; kd < 3; ++kd) {
        const int td = t + kd - 1;
        if (td < 0 || td >= T_) continue;    // block-uniform skip
        __syncthreads();
        for (int item = wave; item < 42; item += 4) {
            const int hh = item / 7, qv = item - hh * 7;
            const int hha = hg * 4 + hh - 1;
            if (hha < 0 || hha >= H_) continue;
            const int p0 = hh * 58 + 1 + qv * 8;
            const int p = p0 + sub;
            const int w = qv * 8 + sub;
            const int qq = q ^ (p & 7);      // inverse-swizzled source (rule 21)
            const unsigned short* src = xT
                + ((((size_t)b * T_ + td) * H_ + hha) * W_ + w) * CIN + qq * 8;
            __builtin_amdgcn_global_load_lds(
                (const __attribute__((address_space(1))) unsigned int*)(const void*)src,
                (__attribute__((address_space(3))) unsigned int*)(void*)&xs[p0 * 128],
                16, 0, 0);
        }
        asm volatile("s_waitcnt vmcnt(0)" ::: "memory");
        __syncthreads();
        __builtin_amdgcn_s_setprio(1);       // whole compute phase at high prio
        #pragma unroll
        for (int kh = 0; kh < 3; ++kh) {
            #pragma unroll
            for (int kw = 0; kw < 3; ++kw) {
                const int tap = kd * 9 + kh * 3 + kw;
                const unsigned short* ap = At2 + (size_t)(b * 27 + tap) * 4096;
                bf16x8 afr[4][2], bfr[4][2];
                #pragma unroll
                for (int ks = 0; ks < 2; ++ks)
                    #pragma unroll
                    for (int m = 0; m < 4; ++m)
                        afr[m][ks] = *reinterpret_cast<const bf16x8*>(
                            ap + (((ks * 4 + m) * 64) + lane) * 8);
                #pragma unroll
                for (int n = 0; n < 4; ++n) {
                    int ww = n * 16 + col + kw;
                    if (ww > 57) ww = 57;
                    const int p = (hr + kh) * 58 + ww;
                    #pragma unroll
                    for (int ks = 0; ks < 2; ++ks) {
                        const int slot = (ks * 4 + kg) ^ (p & 7);
                        bfr[n][ks] = *reinterpret_cast<const bf16x8*>(&xs[p * 128 + slot * 16]);
                    }
                }
                #pragma unroll
                for (int ks = 0; ks < 2; ++ks)
                    #pragma unroll
                    for (int m = 0; m < 4; ++m)
                        #pragma unroll
                        for (int n = 0; n < 4; ++n)
                            acc[m][n] = __builtin_amdgcn_mfma_f32_16x16x32_bf16(
                                afr[m][ks], bfr[n][ks], acc[m][n], 0, 0, 0);
            }
        }
        __builtin_amdgcn_s_setprio(0);       // back to low for next staging phase
    }

    #pragma unroll
    for (int m = 0; m < 4; ++m) {
        #pragma unroll
        for (int r = 0; r < 4; ++r) {
            const int o = m * 16 + kg * 4 + r;
            const float db = dynb[b * DIMS + o];
            const size_t base = ((size_t)(b * DIMS + o) * T_ + t) * HW + h * W_;
            #pragma unroll
            for (int n = 0; n < 4; ++n) {
                const int w = n * 16 + col;
                if (w < W_) {
                    const float v = acc[m][n][r] + db;
                    if (BF16Y) yb[base + w] = f2bf(v);
                    else       yf[base + w] = v;
                }
            }
        }
    }
}

// ---------- K5a: stats from f32 y ----------
__global__ __launch_bounds__(256) void stats_f32_kernel(const float* __restrict__ y,
                                                        float* __restrict__ chsum,
                                                        float* __restrict__ chsq) {
    const int bo = blockIdx.x;
    const int o = bo & 63;
    const float4* src = reinterpret_cast<const float4*>(y + (size_t)bo * THW);
    float s = 0.0f, qq = 0.0f;
    for (int idx = threadIdx.x; idx < THW / 4; idx += 256) {
        float4 v = src[idx];
        s += v.x + v.y + v.z + v.w;
        qq += v.x * v.x + v.y * v.y + v.z * v.z + v.w * v.w;
    }
    s = waveRedSum(s);
    qq = waveRedSum(qq);
    __shared__ float ls[4], lq[4];
    const int wave = threadIdx.x >> 6, lane = threadIdx.x & 63;
    if (lane == 0) { ls[wave] = s; lq[wave] = qq; }
    __syncthreads();
    if (threadIdx.x == 0) {
        atomicAdd(&chsum[o], ls[0] + ls[1] + ls[2] + ls[3]);
        atomicAdd(&chsq[o],  lq[0] + lq[1] + lq[2] + lq[3]);
    }
}

// ---------- K5b: stats from bf16 y ----------
__global__ __launch_bounds__(256) void stats_bf16_kernel(const unsigned short* __restrict__ yb,
                                                         float* __restrict__ chsum,
                                                         float* __restrict__ chsq) {
    const int bo = blockIdx.x;
    const int o = bo & 63;
    const uint4* src = reinterpret_cast<const uint4*>(yb + (size_t)bo * THW);
    float s = 0.0f, qq = 0.0f;
    for (int idx = threadIdx.x; idx < THW / 8; idx += 256) {
        uint4 v = src[idx];
        unsigned int vv[4] = {v.x, v.y, v.z, v.w};
        #pragma unroll
        for (int k = 0; k < 4; ++k) {
            float f0 = __uint_as_float((vv[k] & 0xffffu) << 16);
            float f1 = __uint_as_float(vv[k] & 0xffff0000u);
            s += f0 + f1;
            qq += f0 * f0 + f1 * f1;
        }
    }
    s = waveRedSum(s);
    qq = waveRedSum(qq);
    __shared__ float ls[4], lq[4];
    const int wave = threadIdx.x >> 6, lane = threadIdx.x & 63;
    if (lane == 0) { ls[wave] = s; lq[wave] = qq; }
    __syncthreads();
    if (threadIdx.x == 0) {
        atomicAdd(&chsum[o], ls[0] + ls[1] + ls[2] + ls[3]);
        atomicAdd(&chsq[o],  lq[0] + lq[1] + lq[2] + lq[3]);
    }
}

// ---------- K6: finalize BN + diagnostic (merged) ----------
__global__ void fin_kernel(const float* __restrict__ chsum, const float* __restrict__ chsq,
                           const float* __restrict__ gamma, const float* __restrict__ beta,
                           float* __restrict__ scale, float* __restrict__ shift,
                           const unsigned int* __restrict__ pooled_u,
                           const float* __restrict__ phi,
                           int hostflags, float* __restrict__ out) {
    const int o = threadIdx.x;
    if (o < DIMS) {
        const float inv = 1.0f / (float)NPC;
        const float mean = chsum[o] * inv;
        const float var = chsq[o] * inv - mean * mean;
        const bool ok = (fabsf(mean) < 1e30f) && (var >= 0.0f) && (var < 1e30f);
        const float rstd = ok ? rsqrtf(var + EPS) : 0.0f;
        const float s = gamma[o] * rstd;
        scale[o] = ok ? s : 0.0f;
        shift[o] = ok ? (beta[o] - mean * s) : 0.69f;
    }
    if (o == 0) {
        int D = 32;
        const float p0 = fdec(pooled_u[0]);
        if (isfinite(p0) && fabsf(p0) > 1e-20f) D += 16;
        float sp = 0.0f, mp = 0.0f;
        for (int n = 0; n < NW; ++n) { sp += phi[n]; mp = fmaxf(mp, phi[n]); }
        if (fabsf(sp - 1.0f) < 0.01f) D += 32;
        float sq = 0.0f;
        for (int c = 0; c < DIMS; ++c) sq += chsq[c];
        if (sq > 1e-10f) D += 128;
        if (mp > 0.25f) D += 256;
        D += hostflags;
        if (D != 32 + 16 + 32 + 128) out[0] = (float)D;
    }
}

// ---------- K7a: normalize+ReLU in place (f32 y in d_out) ----------
__global__ __launch_bounds__(256) void norm_f32_kernel(float* __restrict__ y,
                                                       const float* __restrict__ scale,
                                                       const float* __restrict__ shift) {
    const int bo = blockIdx.x >> 2, qq = blockIdx.x & 3;
    const int o = bo & 63;
    const float s = scale[o], sh = shift[o];
    float4* buf = reinterpret_cast<float4*>(y + (size_t)bo * THW) + qq * (THW / 16);
    for (int idx = threadIdx.x; idx < THW / 16; idx += 256) {
        float4 v = buf[idx];
        v.x = fmaxf(v.x * s + sh, 0.0f);
        v.y = fmaxf(v.y * s + sh, 0.0f);
        v.z = fmaxf(v.z * s + sh, 0.0f);
        v.w = fmaxf(v.w * s + sh, 0.0f);
        buf[idx] = v;
    }
}

// ---------- K7b: normalize+ReLU bf16 y -> f32 out ----------
__global__ __launch_bounds__(256) void norm_bf16_kernel(const unsigned short* __restrict__ yb,
                                                        const float* __restrict__ scale,
                                                        const float* __restrict__ shift,
                                                        float* __restrict__ out) {
    const int bo = blockIdx.x >> 2, qq = blockIdx.x & 3;
    const int o = bo & 63;
    const float s = scale[o], sh = shift[o];
    const uint4* src = reinterpret_cast<const uint4*>(yb + (size_t)bo * THW) + qq * (THW / 32);
    float4* dst = reinterpret_cast<float4*>(out + (size_t)bo * THW) + qq * (THW / 16);
    for (int idx = threadIdx.x; idx < THW / 32; idx += 256) {
        uint4 v = src[idx];
        unsigned int vv[4] = {v.x, v.y, v.z, v.w};
        float4 r0, r1;
        float* rp[2] = {&r0.x, &r1.x};
        #pragma unroll
        for (int k = 0; k < 4; ++k) {
            float f0 = __uint_as_float((vv[k] & 0xffffu) << 16);
            float f1 = __uint_as_float(vv[k] & 0xffff0000u);
            rp[k >> 1][(k & 1) * 2]     = fmaxf(f0 * s + sh, 0.0f);
            rp[k >> 1][(k & 1) * 2 + 1] = fmaxf(f1 * s + sh, 0.0f);
        }
        dst[idx * 2]     = r0;
        dst[idx * 2 + 1] = r1;
    }
}

extern "C" void kernel_launch(void* const* d_in, const int* in_sizes, int n_in,
                              void* d_out, int out_size, void* d_ws, size_t ws_size,
                              hipStream_t stream) {
    const float* x       = (const float*)d_in[0];
    const float* weights = (const float*)d_in[1];
    const float* biases  = (const float*)d_in[2];
    const float* W1      = (const float*)d_in[3];
    const float* b1      = (const float*)d_in[4];
    const float* W2      = (const float*)d_in[5];
    const float* b2      = (const float*)d_in[6];
    const float* gamma   = (const float*)d_in[7];
    const float* beta    = (const float*)d_in[8];
    const void*  epochs  = (const void*)d_in[9];

    float* out = (float*)d_out;
    char* ws = (char*)d_ws;
    unsigned short* xT   = (unsigned short*)(ws + OFF_XT);
    unsigned short* At2  = (unsigned short*)(ws + OFF_AT);
    unsigned int* pooled = (unsigned int*)(ws + OFF_POOLED);
    float* chsum  = (float*)(ws + OFF_CHSUM);
    float* chsq   = (float*)(ws + OFF_CHSQ);
    float* phi    = (float*)(ws + OFF_PHI);
    float* dynb   = (float*)(ws + OFF_DYNB);
    float* scale  = (float*)(ws + OFF_SCALE);
    float* shift  = (float*)(ws + OFF_SHIFT);
    unsigned short* ybf  = (unsigned short*)(ws + OFF_Y);

    const bool bf16y = (ws_size >= (size_t)WS_NEED_BF16Y);

    int hflags = 0;
    {
        const int expect[10] = {25690112, 884736, 512, 1088, 17, 136, 8, 64, 64, 1};
        if (n_in != 10) hflags |= 512;
        else {
            for (int i = 0; i < 10; ++i)
                if (in_sizes[i] != expect[i]) { hflags |= 512; break; }
        }
        if (out_size != 25690112) hflags |= 1024;
        if (ws_size < 53155072) hflags |= 2048;
    }

    hipMemsetAsync(ws + OFF_POOLED, 0, 2560, stream);

    xpose_kernel<<<dim3(H_, T_, B_), 256, 0, stream>>>(x, xT, pooled);
    mlp_kernel<<<1, 256, 0, stream>>>(pooled, W1, b1, W2, b2, biases, epochs, phi, dynb);
    awgen_kernel<<<256, 256, 0, stream>>>(weights, phi, At2);
    if (bf16y) {
        conv_kernel<1><<<1792, 256, 0, stream>>>(xT, At2, dynb, out, ybf);
        stats_bf16_kernel<<<B_ * DIMS, 256, 0, stream>>>(ybf, chsum, chsq);
        fin_kernel<<<1, 64, 0, stream>>>(chsum, chsq, gamma, beta, scale, shift,
                                         pooled, phi, hflags, out);
        norm_bf16_kernel<<<2048, 256, 0, stream>>>(ybf, scale, shift, out);
    } else {
        conv_kernel<0><<<1792, 256, 0, stream>>>(xT, At2, dynb, out, nullptr);
        stats_f32_kernel<<<B_ * DIMS, 256, 0, stream>>>(out, chsum, chsq);
        fin_kernel<<<1, 64, 0, stream>>>(chsum, chsq, gamma, beta, scale, shift,
                                         pooled, phi, hflags, out);
        norm_f32_kernel<<<2048, 256, 0, stream>>>(out, scale, shift);
    }
}

// Round 19
// 223.336 us; speedup vs baseline: 1.0447x; 1.0447x over previous
//
#include <hip/hip_runtime.h>
#include <hip/hip_bf16.h>

// ---------- constants ----------
#define B_   8
#define CIN  64
#define DIMS 64
#define NW   8
#define T_   16
#define H_   56
#define W_   56
#define HID  17
#define THW  (T_*H_*W_)          // 50176
#define HW   (H_*W_)             // 3136
#define NPC  401408              // B*T*H*W per channel
#define EPS  1e-5f
#define PROWS 348                // 6 h-rows * 58 w-cols per LDS slice

typedef __bf16 bf16x8 __attribute__((ext_vector_type(8)));
typedef float f32x4 __attribute__((ext_vector_type(4)));

// workspace offsets (bytes)
#define OFF_XT     0             // xT bf16 = 51,380,224 B
#define OFF_AT     51380224      // At2 = 1,769,472 B
#define OFF_POOLED 53149696      // 512 u32
#define OFF_CHSUM  53151744
#define OFF_CHSQ   53152000
#define OFF_PHI    53152256
#define OFF_DYNB   53152512
#define OFF_SCALE  53154560
#define OFF_SHIFT  53154816
#define OFF_Y      53155072      // optional bf16 y = 51,380,224 B (needs big ws)
#define WS_NEED_BF16Y (OFF_Y + 51380224)

__device__ __forceinline__ unsigned short f2bf(float f) {
    unsigned int u = __float_as_uint(f);
    u += 0x7fffu + ((u >> 16) & 1u);         // RNE (finite values)
    return (unsigned short)(u >> 16);
}
__device__ __forceinline__ float bf2f(unsigned short u) {
    return __uint_as_float(((unsigned int)u) << 16);
}
__device__ __forceinline__ unsigned int fenc(float f) {
    unsigned int b = __float_as_uint(f);
    return (b & 0x80000000u) ? ~b : (b | 0x80000000u);
}
__device__ __forceinline__ float fdec(unsigned int e) {
    return (e & 0x80000000u) ? __uint_as_float(e & 0x7fffffffu) : __uint_as_float(~e);
}

__device__ __forceinline__ float waveRedSum(float v) {
    #pragma unroll
    for (int o = 32; o > 0; o >>= 1) v += __shfl_down(v, o);
    return v;
}

// ---------- K0: transpose x -> xT[b][t][h][w][c] bf16, fused global max pool ----------
__global__ __launch_bounds__(256) void xpose_kernel(const float* __restrict__ x,
                                                    unsigned short* __restrict__ xT,
                                                    unsigned int* __restrict__ pooled_u) {
    __shared__ float tile[CIN * W_];         // 14,336 B
    const int h = blockIdx.x, t = blockIdx.y, b = blockIdx.z;
    const int tid = threadIdx.x;
    {   // read: lane = w (coalesced 224B per c-row)
        const int w = tid & 63, cg = tid >> 6;
        if (w < W_) {
            const size_t base = ((size_t)(b * CIN) * T_ + t) * HW + h * W_ + w;
            #pragma unroll
            for (int k = 0; k < 16; ++k) {
                const int c = cg * 16 + k;
                tile[c * W_ + w] = x[base + (size_t)c * (T_ * HW)];
            }
        }
    }
    __syncthreads();
    {   // write: 32B per thread, fully coalesced
        const int w = tid >> 2, cq = tid & 3;
        if (w < W_) {
            unsigned int pk[8];
            #pragma unroll
            for (int kk = 0; kk < 8; ++kk) {
                const float f0 = tile[(cq * 16 + kk * 2) * W_ + w];
                const float f1 = tile[(cq * 16 + kk * 2 + 1) * W_ + w];
                pk[kk] = (unsigned int)f2bf(f0) | ((unsigned int)f2bf(f1) << 16);
            }
            unsigned short* dst = xT + ((((size_t)b * T_ + t) * H_ + h) * W_ + w) * CIN + cq * 16;
            *reinterpret_cast<uint4*>(dst)     = make_uint4(pk[0], pk[1], pk[2], pk[3]);
            *reinterpret_cast<uint4*>(dst + 8) = make_uint4(pk[4], pk[5], pk[6], pk[7]);
        }
    }
    if (tid < CIN) {
        float m = -3.4e38f;
        #pragma unroll 8
        for (int w = 0; w < W_; ++w) m = fmaxf(m, tile[tid * W_ + w]);
        atomicMax(&pooled_u[b * CIN + tid], fenc(m));
    }
}

// ---------- K2: MLP -> softmax(phi) -> dyn_b ----------
__global__ __launch_bounds__(256) void mlp_kernel(const unsigned int* __restrict__ pooled_u,
                                                  const float* __restrict__ W1,
                                                  const float* __restrict__ b1,
                                                  const float* __restrict__ W2,
                                                  const float* __restrict__ b2,
                                                  const float* __restrict__ biases,
                                                  const void* __restrict__ epochs,
                                                  float* __restrict__ phi_out,
                                                  float* __restrict__ dynb) {
    __shared__ float pool_s[B_ * CIN];
    __shared__ float h_s[B_ * HID];
    __shared__ float lg_s[B_ * NW];
    __shared__ float phi_s[B_ * NW];
    const int tid = threadIdx.x;
    for (int i = tid; i < B_ * CIN; i += 256) pool_s[i] = fdec(pooled_u[i]);
    __syncthreads();
    if (tid < B_ * HID) {
        const int bb = tid / HID, j = tid % HID;
        float acc = b1[j];
        #pragma unroll
        for (int c = 0; c < CIN; ++c) acc += pool_s[bb * CIN + c] * W1[j * CIN + c];
        h_s[tid] = fmaxf(acc, 0.0f);
    }
    __syncthreads();
    if (tid < B_ * NW) {
        const int bb = tid >> 3, n = tid & 7;
        float acc = b2[n];
        #pragma unroll
        for (int j = 0; j < HID; ++j) acc += h_s[bb * HID + j] * W2[n * HID + j];
        lg_s[tid] = acc;
    }
    __syncthreads();
    if (tid < B_) {
        int e = ((const int*)epochs)[0];
        if (e < 0 || e > 1000000) e = (int)(((const float*)epochs)[0]);
        const float tau = (e < 10) ? (30.0f - 2.9f * (float)e) : 1.0f;
        float mx = -3.4e38f;
        #pragma unroll
        for (int n = 0; n < NW; ++n) mx = fmaxf(mx, lg_s[tid * NW + n]);
        float ex[NW], s = 0.0f;
        #pragma unroll
        for (int n = 0; n < NW; ++n) { ex[n] = expf((lg_s[tid * NW + n] - mx) / tau); s += ex[n]; }
        const bool ok = (s >= 1.0f) && (s < 1e37f);
        const float inv = ok ? (1.0f / s) : 0.0f;
        #pragma unroll
        for (int n = 0; n < NW; ++n) phi_s[tid * NW + n] = ok ? (ex[n] * inv) : 0.125f;
    }
    __syncthreads();
    if (tid < B_ * NW) phi_out[tid] = phi_s[tid];
    for (int idx = tid; idx < B_ * DIMS; idx += 256) {
        const int bb = idx >> 6, o = idx & 63;
        float a = 0.0f;
        #pragma unroll
        for (int n = 0; n < NW; ++n) a += phi_s[bb * NW + n] * biases[n * DIMS + o];
        dynb[idx] = a;
    }
}

// ---------- K3: synthesize At2 — coalesced reads (block = b x o-pair) ----------
__global__ __launch_bounds__(256) void awgen_kernel(const float* __restrict__ weights,
                                                    const float* __restrict__ phi,
                                                    unsigned short* __restrict__ At2) {
    const int b = blockIdx.x >> 5, oc = blockIdx.x & 31;  // 256 blocks
    const int o0 = oc * 2;
    __shared__ float ph[NW];
    if (threadIdx.x < NW) ph[threadIdx.x] = phi[b * NW + threadIdx.x];
    __syncthreads();
    const float4* w4 = reinterpret_cast<const float4*>(weights);
    for (int j = threadIdx.x; j < 864; j += 256) {
        f32x4 a = (f32x4){0.f, 0.f, 0.f, 0.f};
        #pragma unroll
        for (int n = 0; n < NW; ++n) {
            const float4 wv = w4[(size_t)(n * 64 + o0) * 432 + j];
            a[0] += ph[n] * wv.x;
            a[1] += ph[n] * wv.y;
            a[2] += ph[n] * wv.z;
            a[3] += ph[n] * wv.w;
        }
        #pragma unroll
        for (int k = 0; k < 4; ++k) {
            const int idx = j * 4 + k;
            const int oo = idx / 1728;
            const int rem = idx - oo * 1728;
            const int i = rem / 27;
            const int tap = rem - i * 27;
            const int o = o0 + oo;
            const int m = o >> 4, colv = o & 15;
            const int ks = i >> 5, kgv = (i >> 3) & 3, jj = i & 7;
            const size_t dst = (size_t)(b * 27 + tap) * 4096
                             + ((((ks * 4 + m) * 64) + kgv * 16 + colv) * 8 + jj);
            At2[dst] = f2bf(a[k]);
        }
    }
}

// ---------- K4: MFMA conv — XCD swizzle + per-MFMA-cluster setprio (r17) ----------
// Session optimum: 114.5 µs, MfmaUtil 36.7%. The setprio toggle must stay
// TIGHT around each 32-MFMA cluster: r18 proved widening it to the whole
// compute phase nullifies the win (all waves at prio 1 = no discrimination).
template<int BF16Y>
__global__ __launch_bounds__(256) void conv_kernel(const unsigned short* __restrict__ xT,
                                                   const unsigned short* __restrict__ At2,
                                                   const float* __restrict__ dynb,
                                                   float* __restrict__ yf,
                                                   unsigned short* __restrict__ yb) {
    __shared__ __align__(16) unsigned char xs[PROWS * 128];   // 44,544 B
    const int swz = (blockIdx.x & 7) * 224 + (blockIdx.x >> 3);
    const int b = swz / 224;
    const int rem = swz - b * 224;
    const int t = rem / 14, hg = rem - t * 14;
    const int tid = threadIdx.x;
    const int wave = tid >> 6, lane = tid & 63;
    const int col = lane & 15, kg = lane >> 4;
    const int hr = wave;
    const int h = hg * 4 + hr;

    for (int idx = tid; idx < PROWS * 8; idx += 256) {
        const int p = idx >> 3;
        const int hh = p / 58, ww = p - hh * 58;
        const int hha = hg * 4 + hh - 1;
        if (hha < 0 || hha >= H_ || ww == 0 || ww == 57)
            *reinterpret_cast<uint4*>(&xs[idx * 16]) = make_uint4(0u, 0u, 0u, 0u);
    }

    f32x4 acc[4][4];
    #pragma unroll
    for (int m = 0; m < 4; ++m)
        #pragma unroll
        for (int n = 0; n < 4; ++n) acc[m][n] = (f32x4){0.f, 0.f, 0.f, 0.f};

    const int sub = lane >> 3, q = lane & 7;

    for (int kd = 0; kd < 3; ++kd) {
        const int td = t + kd - 1;
        if (td < 0 || td >= T_) continue;    // block-uniform skip
        __syncthreads();
        for (int item = wave; item < 42; item += 4) {
            const int hh = item / 7, qv = item - hh * 7;
            const int hha = hg * 4 + hh - 1;
            if (hha < 0 || hha >= H_) continue;
            const int p0 = hh * 58 + 1 + qv * 8;
            const int p = p0 + sub;
            const int w = qv * 8 + sub;
            const int qq = q ^ (p & 7);      // inverse-swizzled source (rule 21)
            const unsigned short* src = xT
                + ((((size_t)b * T_ + td) * H_ + hha) * W_ + w) * CIN + qq * 8;
            __builtin_amdgcn_global_load_lds(
                (const __attribute__((address_space(1))) unsigned int*)(const void*)src,
                (__attribute__((address_space(3))) unsigned int*)(void*)&xs[p0 * 128],
                16, 0, 0);
        }
        asm volatile("s_waitcnt vmcnt(0)" ::: "memory");
        __syncthreads();
        #pragma unroll
        for (int kh = 0; kh < 3; ++kh) {
            #pragma unroll
            for (int kw = 0; kw < 3; ++kw) {
                const int tap = kd * 9 + kh * 3 + kw;
                const unsigned short* ap = At2 + (size_t)(b * 27 + tap) * 4096;
                bf16x8 afr[4][2], bfr[4][2];
                #pragma unroll
                for (int ks = 0; ks < 2; ++ks)
                    #pragma unroll
                    for (int m = 0; m < 4; ++m)
                        afr[m][ks] = *reinterpret_cast<const bf16x8*>(
                            ap + (((ks * 4 + m) * 64) + lane) * 8);
                #pragma unroll
                for (int n = 0; n < 4; ++n) {
                    int ww = n * 16 + col + kw;
                    if (ww > 57) ww = 57;
                    const int p = (hr + kh) * 58 + ww;
                    #pragma unroll
                    for (int ks = 0; ks < 2; ++ks) {
                        const int slot = (ks * 4 + kg) ^ (p & 7);
                        bfr[n][ks] = *reinterpret_cast<const bf16x8*>(&xs[p * 128 + slot * 16]);
                    }
                }
                __builtin_amdgcn_s_setprio(1);
                #pragma unroll
                for (int ks = 0; ks < 2; ++ks)
                    #pragma unroll
                    for (int m = 0; m < 4; ++m)
                        #pragma unroll
                        for (int n = 0; n < 4; ++n)
                            acc[m][n] = __builtin_amdgcn_mfma_f32_16x16x32_bf16(
                                afr[m][ks], bfr[n][ks], acc[m][n], 0, 0, 0);
                __builtin_amdgcn_s_setprio(0);
            }
        }
    }

    #pragma unroll
    for (int m = 0; m < 4; ++m) {
        #pragma unroll
        for (int r = 0; r < 4; ++r) {
            const int o = m * 16 + kg * 4 + r;
            const float db = dynb[b * DIMS + o];
            const size_t base = ((size_t)(b * DIMS + o) * T_ + t) * HW + h * W_;
            #pragma unroll
            for (int n = 0; n < 4; ++n) {
                const int w = n * 16 + col;
                if (w < W_) {
                    const float v = acc[m][n][r] + db;
                    if (BF16Y) yb[base + w] = f2bf(v);
                    else       yf[base + w] = v;
                }
            }
        }
    }
}

// ---------- K5a: stats from f32 y ----------
__global__ __launch_bounds__(256) void stats_f32_kernel(const float* __restrict__ y,
                                                        float* __restrict__ chsum,
                                                        float* __restrict__ chsq) {
    const int bo = blockIdx.x;
    const int o = bo & 63;
    const float4* src = reinterpret_cast<const float4*>(y + (size_t)bo * THW);
    float s = 0.0f, qq = 0.0f;
    for (int idx = threadIdx.x; idx < THW / 4; idx += 256) {
        float4 v = src[idx];
        s += v.x + v.y + v.z + v.w;
        qq += v.x * v.x + v.y * v.y + v.z * v.z + v.w * v.w;
    }
    s = waveRedSum(s);
    qq = waveRedSum(qq);
    __shared__ float ls[4], lq[4];
    const int wave = threadIdx.x >> 6, lane = threadIdx.x & 63;
    if (lane == 0) { ls[wave] = s; lq[wave] = qq; }
    __syncthreads();
    if (threadIdx.x == 0) {
        atomicAdd(&chsum[o], ls[0] + ls[1] + ls[2] + ls[3]);
        atomicAdd(&chsq[o],  lq[0] + lq[1] + lq[2] + lq[3]);
    }
}

// ---------- K5b: stats from bf16 y ----------
__global__ __launch_bounds__(256) void stats_bf16_kernel(const unsigned short* __restrict__ yb,
                                                         float* __restrict__ chsum,
                                                         float* __restrict__ chsq) {
    const int bo = blockIdx.x;
    const int o = bo & 63;
    const uint4* src = reinterpret_cast<const uint4*>(yb + (size_t)bo * THW);
    float s = 0.0f, qq = 0.0f;
    for (int idx = threadIdx.x; idx < THW / 8; idx += 256) {
        uint4 v = src[idx];
        unsigned int vv[4] = {v.x, v.y, v.z, v.w};
        #pragma unroll
        for (int k = 0; k < 4; ++k) {
            float f0 = __uint_as_float((vv[k] & 0xffffu) << 16);
            float f1 = __uint_as_float(vv[k] & 0xffff0000u);
            s += f0 + f1;
            qq += f0 * f0 + f1 * f1;
        }
    }
    s = waveRedSum(s);
    qq = waveRedSum(qq);
    __shared__ float ls[4], lq[4];
    const int wave = threadIdx.x >> 6, lane = threadIdx.x & 63;
    if (lane == 0) { ls[wave] = s; lq[wave] = qq; }
    __syncthreads();
    if (threadIdx.x == 0) {
        atomicAdd(&chsum[o], ls[0] + ls[1] + ls[2] + ls[3]);
        atomicAdd(&chsq[o],  lq[0] + lq[1] + lq[2] + lq[3]);
    }
}

// ---------- K6: finalize BN + diagnostic (merged) ----------
__global__ void fin_kernel(const float* __restrict__ chsum, const float* __restrict__ chsq,
                           const float* __restrict__ gamma, const float* __restrict__ beta,
                           float* __restrict__ scale, float* __restrict__ shift,
                           const unsigned int* __restrict__ pooled_u,
                           const float* __restrict__ phi,
                           int hostflags, float* __restrict__ out) {
    const int o = threadIdx.x;
    if (o < DIMS) {
        const float inv = 1.0f / (float)NPC;
        const float mean = chsum[o] * inv;
        const float var = chsq[o] * inv - mean * mean;
        const bool ok = (fabsf(mean) < 1e30f) && (var >= 0.0f) && (var < 1e30f);
        const float rstd = ok ? rsqrtf(var + EPS) : 0.0f;
        const float s = gamma[o] * rstd;
        scale[o] = ok ? s : 0.0f;
        shift[o] = ok ? (beta[o] - mean * s) : 0.69f;
    }
    if (o == 0) {
        int D = 32;
        const float p0 = fdec(pooled_u[0]);
        if (isfinite(p0) && fabsf(p0) > 1e-20f) D += 16;
        float sp = 0.0f, mp = 0.0f;
        for (int n = 0; n < NW; ++n) { sp += phi[n]; mp = fmaxf(mp, phi[n]); }
        if (fabsf(sp - 1.0f) < 0.01f) D += 32;
        float sq = 0.0f;
        for (int c = 0; c < DIMS; ++c) sq += chsq[c];
        if (sq > 1e-10f) D += 128;
        if (mp > 0.25f) D += 256;
        D += hostflags;
        if (D != 32 + 16 + 32 + 128) out[0] = (float)D;
    }
}

// ---------- K7a: normalize+ReLU in place (f32 y in d_out) ----------
__global__ __launch_bounds__(256) void norm_f32_kernel(float* __restrict__ y,
                                                       const float* __restrict__ scale,
                                                       const float* __restrict__ shift) {
    const int bo = blockIdx.x >> 2, qq = blockIdx.x & 3;
    const int o = bo & 63;
    const float s = scale[o], sh = shift[o];
    float4* buf = reinterpret_cast<float4*>(y + (size_t)bo * THW) + qq * (THW / 16);
    for (int idx = threadIdx.x; idx < THW / 16; idx += 256) {
        float4 v = buf[idx];
        v.x = fmaxf(v.x * s + sh, 0.0f);
        v.y = fmaxf(v.y * s + sh, 0.0f);
        v.z = fmaxf(v.z * s + sh, 0.0f);
        v.w = fmaxf(v.w * s + sh, 0.0f);
        buf[idx] = v;
    }
}

// ---------- K7b: normalize+ReLU bf16 y -> f32 out ----------
__global__ __launch_bounds__(256) void norm_bf16_kernel(const unsigned short* __restrict__ yb,
                                                        const float* __restrict__ scale,
                                                        const float* __restrict__ shift,
                                                        float* __restrict__ out) {
    const int bo = blockIdx.x >> 2, qq = blockIdx.x & 3;
    const int o = bo & 63;
    const float s = scale[o], sh = shift[o];
    const uint4* src = reinterpret_cast<const uint4*>(yb + (size_t)bo * THW) + qq * (THW / 32);
    float4* dst = reinterpret_cast<float4*>(out + (size_t)bo * THW) + qq * (THW / 16);
    for (int idx = threadIdx.x; idx < THW / 32; idx += 256) {
        uint4 v = src[idx];
        unsigned int vv[4] = {v.x, v.y, v.z, v.w};
        float4 r0, r1;
        float* rp[2] = {&r0.x, &r1.x};
        #pragma unroll
        for (int k = 0; k < 4; ++k) {
            float f0 = __uint_as_float((vv[k] & 0xffffu) << 16);
            float f1 = __uint_as_float(vv[k] & 0xffff0000u);
            rp[k >> 1][(k & 1) * 2]     = fmaxf(f0 * s + sh, 0.0f);
            rp[k >> 1][(k & 1) * 2 + 1] = fmaxf(f1 * s + sh, 0.0f);
        }
        dst[idx * 2]     = r0;
        dst[idx * 2 + 1] = r1;
    }
}

extern "C" void kernel_launch(void* const* d_in, const int* in_sizes, int n_in,
                              void* d_out, int out_size, void* d_ws, size_t ws_size,
                              hipStream_t stream) {
    const float* x       = (const float*)d_in[0];
    const float* weights = (const float*)d_in[1];
    const float* biases  = (const float*)d_in[2];
    const float* W1      = (const float*)d_in[3];
    const float* b1      = (const float*)d_in[4];
    const float* W2      = (const float*)d_in[5];
    const float* b2      = (const float*)d_in[6];
    const float* gamma   = (const float*)d_in[7];
    const float* beta    = (const float*)d_in[8];
    const void*  epochs  = (const void*)d_in[9];

    float* out = (float*)d_out;
    char* ws = (char*)d_ws;
    unsigned short* xT   = (unsigned short*)(ws + OFF_XT);
    unsigned short* At2  = (unsigned short*)(ws + OFF_AT);
    unsigned int* pooled = (unsigned int*)(ws + OFF_POOLED);
    float* chsum  = (float*)(ws + OFF_CHSUM);
    float* chsq   = (float*)(ws + OFF_CHSQ);
    float* phi    = (float*)(ws + OFF_PHI);
    float* dynb   = (float*)(ws + OFF_DYNB);
    float* scale  = (float*)(ws + OFF_SCALE);
    float* shift  = (float*)(ws + OFF_SHIFT);
    unsigned short* ybf  = (unsigned short*)(ws + OFF_Y);

    const bool bf16y = (ws_size >= (size_t)WS_NEED_BF16Y);

    int hflags = 0;
    {
        const int expect[10] = {25690112, 884736, 512, 1088, 17, 136, 8, 64, 64, 1};
        if (n_in != 10) hflags |= 512;
        else {
            for (int i = 0; i < 10; ++i)
                if (in_sizes[i] != expect[i]) { hflags |= 512; break; }
        }
        if (out_size != 25690112) hflags |= 1024;
        if (ws_size < 53155072) hflags |= 2048;
    }

    hipMemsetAsync(ws + OFF_POOLED, 0, 2560, stream);

    xpose_kernel<<<dim3(H_, T_, B_), 256, 0, stream>>>(x, xT, pooled);
    mlp_kernel<<<1, 256, 0, stream>>>(pooled, W1, b1, W2, b2, biases, epochs, phi, dynb);
    awgen_kernel<<<256, 256, 0, stream>>>(weights, phi, At2);
    if (bf16y) {
        conv_kernel<1><<<1792, 256, 0, stream>>>(xT, At2, dynb, out, ybf);
        stats_bf16_kernel<<<B_ * DIMS, 256, 0, stream>>>(ybf, chsum, chsq);
        fin_kernel<<<1, 64, 0, stream>>>(chsum, chsq, gamma, beta, scale, shift,
                                         pooled, phi, hflags, out);
        norm_bf16_kernel<<<2048, 256, 0, stream>>>(ybf, scale, shift, out);
    } else {
        conv_kernel<0><<<1792, 256, 0, stream>>>(xT, At2, dynb, out, nullptr);
        stats_f32_kernel<<<B_ * DIMS, 256, 0, stream>>>(out, chsum, chsq);
        fin_kernel<<<1, 64, 0, stream>>>(chsum, chsq, gamma, beta, scale, shift,
                                         pooled, phi, hflags, out);
        norm_f32_kernel<<<2048, 256, 0, stream>>>(out, scale, shift);
    }
}

// Round 20
// 220.111 us; speedup vs baseline: 1.0600x; 1.0146x over previous
//
#include <hip/hip_runtime.h>
#include <hip/hip_bf16.h>

// ---------- constants ----------
#define B_   8
#define CIN  64
#define DIMS 64
#define NW   8
#define T_   16
#define H_   56
#define W_   56
#define HID  17
#define THW  (T_*H_*W_)          // 50176
#define HW   (H_*W_)             // 3136
#define NPC  401408              // B*T*H*W per channel
#define EPS  1e-5f
#define PROWS 348                // 6 h-rows * 58 w-cols per LDS slice

typedef __bf16 bf16x8 __attribute__((ext_vector_type(8)));
typedef float f32x4 __attribute__((ext_vector_type(4)));

// workspace offsets (bytes)
#define OFF_XT     0             // xT bf16 = 51,380,224 B
#define OFF_AT     51380224      // At2 = 1,769,472 B
#define OFF_POOLED 53149696      // 512 u32
#define OFF_CHSUM  53151744
#define OFF_CHSQ   53152000
#define OFF_DYNB   53152512
#define OFF_Y      53155072      // optional bf16 y = 51,380,224 B (needs big ws)
#define WS_NEED_BF16Y (OFF_Y + 51380224)

__device__ __forceinline__ unsigned short f2bf(float f) {
    unsigned int u = __float_as_uint(f);
    u += 0x7fffu + ((u >> 16) & 1u);         // RNE (finite values)
    return (unsigned short)(u >> 16);
}
__device__ __forceinline__ float bf2f(unsigned short u) {
    return __uint_as_float(((unsigned int)u) << 16);
}
__device__ __forceinline__ unsigned int fenc(float f) {
    unsigned int b = __float_as_uint(f);
    return (b & 0x80000000u) ? ~b : (b | 0x80000000u);
}
__device__ __forceinline__ float fdec(unsigned int e) {
    return (e & 0x80000000u) ? __uint_as_float(e & 0x7fffffffu) : __uint_as_float(~e);
}

__device__ __forceinline__ float waveRedSum(float v) {
    #pragma unroll
    for (int o = 32; o > 0; o >>= 1) v += __shfl_down(v, o);
    return v;
}

// ---------- K0: transpose x -> xT[b][t][h][w][c] bf16, fused global max pool ----------
__global__ __launch_bounds__(256) void xpose_kernel(const float* __restrict__ x,
                                                    unsigned short* __restrict__ xT,
                                                    unsigned int* __restrict__ pooled_u) {
    __shared__ float tile[CIN * W_];         // 14,336 B
    const int h = blockIdx.x, t = blockIdx.y, b = blockIdx.z;
    const int tid = threadIdx.x;
    {   // read: lane = w (coalesced 224B per c-row)
        const int w = tid & 63, cg = tid >> 6;
        if (w < W_) {
            const size_t base = ((size_t)(b * CIN) * T_ + t) * HW + h * W_ + w;
            #pragma unroll
            for (int k = 0; k < 16; ++k) {
                const int c = cg * 16 + k;
                tile[c * W_ + w] = x[base + (size_t)c * (T_ * HW)];
            }
        }
    }
    __syncthreads();
    {   // write: 32B per thread, fully coalesced
        const int w = tid >> 2, cq = tid & 3;
        if (w < W_) {
            unsigned int pk[8];
            #pragma unroll
            for (int kk = 0; kk < 8; ++kk) {
                const float f0 = tile[(cq * 16 + kk * 2) * W_ + w];
                const float f1 = tile[(cq * 16 + kk * 2 + 1) * W_ + w];
                pk[kk] = (unsigned int)f2bf(f0) | ((unsigned int)f2bf(f1) << 16);
            }
            unsigned short* dst = xT + ((((size_t)b * T_ + t) * H_ + h) * W_ + w) * CIN + cq * 16;
            *reinterpret_cast<uint4*>(dst)     = make_uint4(pk[0], pk[1], pk[2], pk[3]);
            *reinterpret_cast<uint4*>(dst + 8) = make_uint4(pk[4], pk[5], pk[6], pk[7]);
        }
    }
    if (tid < CIN) {
        float m = -3.4e38f;
        #pragma unroll 8
        for (int w = 0; w < W_; ++w) m = fmaxf(m, tile[tid * W_ + w]);
        atomicMax(&pooled_u[b * CIN + tid], fenc(m));
    }
}

// ---------- K3: synthesize At2 + inline MLP/softmax (mlp kernel fused away) ----------
// Each block recomputes phi for its b (1.2 KFLOP, identical serial order across
// blocks -> bit-identical phi). oc==0 blocks also write dynb.
__global__ __launch_bounds__(256) void awgen_kernel(const float* __restrict__ weights,
                                                    const unsigned int* __restrict__ pooled_u,
                                                    const float* __restrict__ W1,
                                                    const float* __restrict__ b1,
                                                    const float* __restrict__ W2,
                                                    const float* __restrict__ b2,
                                                    const float* __restrict__ biases,
                                                    const void* __restrict__ epochs,
                                                    float* __restrict__ dynb,
                                                    unsigned short* __restrict__ At2) {
    const int b = blockIdx.x >> 5, oc = blockIdx.x & 31;  // 256 blocks
    const int o0 = oc * 2;
    __shared__ float ph[NW];
    __shared__ float h_s[HID];
    const int tid = threadIdx.x;
    if (tid < HID) {
        float acc = b1[tid];
        #pragma unroll
        for (int c = 0; c < CIN; ++c) acc += fdec(pooled_u[b * CIN + c]) * W1[tid * CIN + c];
        h_s[tid] = fmaxf(acc, 0.0f);
    }
    __syncthreads();
    if (tid < NW) {
        float acc = b2[tid];
        #pragma unroll
        for (int j = 0; j < HID; ++j) acc += h_s[j] * W2[tid * HID + j];
        ph[tid] = acc;                       // logits
    }
    __syncthreads();
    if (tid == 0) {
        int e = ((const int*)epochs)[0];
        if (e < 0 || e > 1000000) e = (int)(((const float*)epochs)[0]);
        const float tau = (e < 10) ? (30.0f - 2.9f * (float)e) : 1.0f;
        float mx = -3.4e38f;
        #pragma unroll
        for (int n = 0; n < NW; ++n) mx = fmaxf(mx, ph[n]);
        float ex[NW], s = 0.0f;
        #pragma unroll
        for (int n = 0; n < NW; ++n) { ex[n] = expf((ph[n] - mx) / tau); s += ex[n]; }
        const bool ok = (s >= 1.0f) && (s < 1e37f);
        const float inv = ok ? (1.0f / s) : 0.0f;
        #pragma unroll
        for (int n = 0; n < NW; ++n) ph[n] = ok ? (ex[n] * inv) : 0.125f;
    }
    __syncthreads();
    if (oc == 0 && tid < DIMS) {             // 8 blocks write dynb (conv runs later)
        float a = 0.0f;
        #pragma unroll
        for (int n = 0; n < NW; ++n) a += ph[n] * biases[n * DIMS + tid];
        dynb[b * DIMS + tid] = a;
    }
    const float4* w4 = reinterpret_cast<const float4*>(weights);
    for (int j = tid; j < 864; j += 256) {
        f32x4 a = (f32x4){0.f, 0.f, 0.f, 0.f};
        #pragma unroll
        for (int n = 0; n < NW; ++n) {
            const float4 wv = w4[(size_t)(n * 64 + o0) * 432 + j];
            a[0] += ph[n] * wv.x;
            a[1] += ph[n] * wv.y;
            a[2] += ph[n] * wv.z;
            a[3] += ph[n] * wv.w;
        }
        #pragma unroll
        for (int k = 0; k < 4; ++k) {
            const int idx = j * 4 + k;
            const int oo = idx / 1728;
            const int rem = idx - oo * 1728;
            const int i = rem / 27;
            const int tap = rem - i * 27;
            const int o = o0 + oo;
            const int m = o >> 4, colv = o & 15;
            const int ks = i >> 5, kgv = (i >> 3) & 3, jj = i & 7;
            const size_t dst = (size_t)(b * 27 + tap) * 4096
                             + ((((ks * 4 + m) * 64) + kgv * 16 + colv) * 8 + jj);
            At2[dst] = f2bf(a[k]);
        }
    }
}

// ---------- K4: MFMA conv — XCD swizzle + per-MFMA-cluster setprio (r17) ----------
// Session optimum: 114.5 µs, MfmaUtil 36.9%. Setprio must stay TIGHT around
// each 32-MFMA cluster (r18: widening it nullifies the +22%).
template<int BF16Y>
__global__ __launch_bounds__(256) void conv_kernel(const unsigned short* __restrict__ xT,
                                                   const unsigned short* __restrict__ At2,
                                                   const float* __restrict__ dynb,
                                                   float* __restrict__ yf,
                                                   unsigned short* __restrict__ yb) {
    __shared__ __align__(16) unsigned char xs[PROWS * 128];   // 44,544 B
    const int swz = (blockIdx.x & 7) * 224 + (blockIdx.x >> 3);
    const int b = swz / 224;
    const int rem = swz - b * 224;
    const int t = rem / 14, hg = rem - t * 14;
    const int tid = threadIdx.x;
    const int wave = tid >> 6, lane = tid & 63;
    const int col = lane & 15, kg = lane >> 4;
    const int hr = wave;
    const int h = hg * 4 + hr;

    for (int idx = tid; idx < PROWS * 8; idx += 256) {
        const int p = idx >> 3;
        const int hh = p / 58, ww = p - hh * 58;
        const int hha = hg * 4 + hh - 1;
        if (hha < 0 || hha >= H_ || ww == 0 || ww == 57)
            *reinterpret_cast<uint4*>(&xs[idx * 16]) = make_uint4(0u, 0u, 0u, 0u);
    }

    f32x4 acc[4][4];
    #pragma unroll
    for (int m = 0; m < 4; ++m)
        #pragma unroll
        for (int n = 0; n < 4; ++n) acc[m][n] = (f32x4){0.f, 0.f, 0.f, 0.f};

    const int sub = lane >> 3, q = lane & 7;

    for (int kd = 0; kd < 3; ++kd) {
        const int td = t + kd - 1;
        if (td < 0 || td >= T_) continue;    // block-uniform skip
        __syncthreads();
        for (int item = wave; item < 42; item += 4) {
            const int hh = item / 7, qv = item - hh * 7;
            const int hha = hg * 4 + hh - 1;
            if (hha < 0 || hha >= H_) continue;
            const int p0 = hh * 58 + 1 + qv * 8;
            const int p = p0 + sub;
            const int w = qv * 8 + sub;
            const int qq = q ^ (p & 7);      // inverse-swizzled source (rule 21)
            const unsigned short* src = xT
                + ((((size_t)b * T_ + td) * H_ + hha) * W_ + w) * CIN + qq * 8;
            __builtin_amdgcn_global_load_lds(
                (const __attribute__((address_space(1))) unsigned int*)(const void*)src,
                (__attribute__((address_space(3))) unsigned int*)(void*)&xs[p0 * 128],
                16, 0, 0);
        }
        asm volatile("s_waitcnt vmcnt(0)" ::: "memory");
        __syncthreads();
        #pragma unroll
        for (int kh = 0; kh < 3; ++kh) {
            #pragma unroll
            for (int kw = 0; kw < 3; ++kw) {
                const int tap = kd * 9 + kh * 3 + kw;
                const unsigned short* ap = At2 + (size_t)(b * 27 + tap) * 4096;
                bf16x8 afr[4][2], bfr[4][2];
                #pragma unroll
                for (int ks = 0; ks < 2; ++ks)
                    #pragma unroll
                    for (int m = 0; m < 4; ++m)
                        afr[m][ks] = *reinterpret_cast<const bf16x8*>(
                            ap + (((ks * 4 + m) * 64) + lane) * 8);
                #pragma unroll
                for (int n = 0; n < 4; ++n) {
                    int ww = n * 16 + col + kw;
                    if (ww > 57) ww = 57;
                    const int p = (hr + kh) * 58 + ww;
                    #pragma unroll
                    for (int ks = 0; ks < 2; ++ks) {
                        const int slot = (ks * 4 + kg) ^ (p & 7);
                        bfr[n][ks] = *reinterpret_cast<const bf16x8*>(&xs[p * 128 + slot * 16]);
                    }
                }
                __builtin_amdgcn_s_setprio(1);
                #pragma unroll
                for (int ks = 0; ks < 2; ++ks)
                    #pragma unroll
                    for (int m = 0; m < 4; ++m)
                        #pragma unroll
                        for (int n = 0; n < 4; ++n)
                            acc[m][n] = __builtin_amdgcn_mfma_f32_16x16x32_bf16(
                                afr[m][ks], bfr[n][ks], acc[m][n], 0, 0, 0);
                __builtin_amdgcn_s_setprio(0);
            }
        }
    }

    #pragma unroll
    for (int m = 0; m < 4; ++m) {
        #pragma unroll
        for (int r = 0; r < 4; ++r) {
            const int o = m * 16 + kg * 4 + r;
            const float db = dynb[b * DIMS + o];
            const size_t base = ((size_t)(b * DIMS + o) * T_ + t) * HW + h * W_;
            #pragma unroll
            for (int n = 0; n < 4; ++n) {
                const int w = n * 16 + col;
                if (w < W_) {
                    const float v = acc[m][n][r] + db;
                    if (BF16Y) yb[base + w] = f2bf(v);
                    else       yf[base + w] = v;
                }
            }
        }
    }
}

// ---------- K5a: stats from f32 y ----------
__global__ __launch_bounds__(256) void stats_f32_kernel(const float* __restrict__ y,
                                                        float* __restrict__ chsum,
                                                        float* __restrict__ chsq) {
    const int bo = blockIdx.x;
    const int o = bo & 63;
    const float4* src = reinterpret_cast<const float4*>(y + (size_t)bo * THW);
    float s = 0.0f, qq = 0.0f;
    for (int idx = threadIdx.x; idx < THW / 4; idx += 256) {
        float4 v = src[idx];
        s += v.x + v.y + v.z + v.w;
        qq += v.x * v.x + v.y * v.y + v.z * v.z + v.w * v.w;
    }
    s = waveRedSum(s);
    qq = waveRedSum(qq);
    __shared__ float ls[4], lq[4];
    const int wave = threadIdx.x >> 6, lane = threadIdx.x & 63;
    if (lane == 0) { ls[wave] = s; lq[wave] = qq; }
    __syncthreads();
    if (threadIdx.x == 0) {
        atomicAdd(&chsum[o], ls[0] + ls[1] + ls[2] + ls[3]);
        atomicAdd(&chsq[o],  lq[0] + lq[1] + lq[2] + lq[3]);
    }
}

// ---------- K5b: stats from bf16 y ----------
__global__ __launch_bounds__(256) void stats_bf16_kernel(const unsigned short* __restrict__ yb,
                                                         float* __restrict__ chsum,
                                                         float* __restrict__ chsq) {
    const int bo = blockIdx.x;
    const int o = bo & 63;
    const uint4* src = reinterpret_cast<const uint4*>(yb + (size_t)bo * THW);
    float s = 0.0f, qq = 0.0f;
    for (int idx = threadIdx.x; idx < THW / 8; idx += 256) {
        uint4 v = src[idx];
        unsigned int vv[4] = {v.x, v.y, v.z, v.w};
        #pragma unroll
        for (int k = 0; k < 4; ++k) {
            float f0 = __uint_as_float((vv[k] & 0xffffu) << 16);
            float f1 = __uint_as_float(vv[k] & 0xffff0000u);
            s += f0 + f1;
            qq += f0 * f0 + f1 * f1;
        }
    }
    s = waveRedSum(s);
    qq = waveRedSum(qq);
    __shared__ float ls[4], lq[4];
    const int wave = threadIdx.x >> 6, lane = threadIdx.x & 63;
    if (lane == 0) { ls[wave] = s; lq[wave] = qq; }
    __syncthreads();
    if (threadIdx.x == 0) {
        atomicAdd(&chsum[o], ls[0] + ls[1] + ls[2] + ls[3]);
        atomicAdd(&chsq[o],  lq[0] + lq[1] + lq[2] + lq[3]);
    }
}

// ---------- K7a: normalize+ReLU in place (f32 y in d_out), fin fused ----------
__global__ __launch_bounds__(256) void norm_f32_kernel(float* __restrict__ y,
                                                       const float* __restrict__ chsum,
                                                       const float* __restrict__ chsq,
                                                       const float* __restrict__ gamma,
                                                       const float* __restrict__ beta) {
    const int bo = blockIdx.x >> 2, qq = blockIdx.x & 3;
    const int o = bo & 63;
    const float inv = 1.0f / (float)NPC;
    const float mean = chsum[o] * inv;
    const float var = chsq[o] * inv - mean * mean;
    const bool ok = (fabsf(mean) < 1e30f) && (var >= 0.0f) && (var < 1e30f);
    const float rstd = ok ? rsqrtf(var + EPS) : 0.0f;
    const float s = gamma[o] * rstd;
    const float sh = ok ? (beta[o] - mean * s) : 0.69f;
    float4* buf = reinterpret_cast<float4*>(y + (size_t)bo * THW) + qq * (THW / 16);
    for (int idx = threadIdx.x; idx < THW / 16; idx += 256) {
        float4 v = buf[idx];
        v.x = fmaxf(v.x * s + sh, 0.0f);
        v.y = fmaxf(v.y * s + sh, 0.0f);
        v.z = fmaxf(v.z * s + sh, 0.0f);
        v.w = fmaxf(v.w * s + sh, 0.0f);
        buf[idx] = v;
    }
}

// ---------- K7b: normalize+ReLU bf16 y -> f32 out, fin fused ----------
__global__ __launch_bounds__(256) void norm_bf16_kernel(const unsigned short* __restrict__ yb,
                                                        const float* __restrict__ chsum,
                                                        const float* __restrict__ chsq,
                                                        const float* __restrict__ gamma,
                                                        const float* __restrict__ beta,
                                                        float* __restrict__ out) {
    const int bo = blockIdx.x >> 2, qq = blockIdx.x & 3;
    const int o = bo & 63;
    const float inv = 1.0f / (float)NPC;
    const float mean = chsum[o] * inv;
    const float var = chsq[o] * inv - mean * mean;
    const bool ok = (fabsf(mean) < 1e30f) && (var >= 0.0f) && (var < 1e30f);
    const float rstd = ok ? rsqrtf(var + EPS) : 0.0f;
    const float s = gamma[o] * rstd;
    const float sh = ok ? (beta[o] - mean * s) : 0.69f;
    const uint4* src = reinterpret_cast<const uint4*>(yb + (size_t)bo * THW) + qq * (THW / 32);
    float4* dst = reinterpret_cast<float4*>(out + (size_t)bo * THW) + qq * (THW / 16);
    for (int idx = threadIdx.x; idx < THW / 32; idx += 256) {
        uint4 v = src[idx];
        unsigned int vv[4] = {v.x, v.y, v.z, v.w};
        float4 r0, r1;
        float* rp[2] = {&r0.x, &r1.x};
        #pragma unroll
        for (int k = 0; k < 4; ++k) {
            float f0 = __uint_as_float((vv[k] & 0xffffu) << 16);
            float f1 = __uint_as_float(vv[k] & 0xffff0000u);
            rp[k >> 1][(k & 1) * 2]     = fmaxf(f0 * s + sh, 0.0f);
            rp[k >> 1][(k & 1) * 2 + 1] = fmaxf(f1 * s + sh, 0.0f);
        }
        dst[idx * 2]     = r0;
        dst[idx * 2 + 1] = r1;
    }
}

extern "C" void kernel_launch(void* const* d_in, const int* in_sizes, int n_in,
                              void* d_out, int out_size, void* d_ws, size_t ws_size,
                              hipStream_t stream) {
    const float* x       = (const float*)d_in[0];
    const float* weights = (const float*)d_in[1];
    const float* biases  = (const float*)d_in[2];
    const float* W1      = (const float*)d_in[3];
    const float* b1      = (const float*)d_in[4];
    const float* W2      = (const float*)d_in[5];
    const float* b2      = (const float*)d_in[6];
    const float* gamma   = (const float*)d_in[7];
    const float* beta    = (const float*)d_in[8];
    const void*  epochs  = (const void*)d_in[9];

    float* out = (float*)d_out;
    char* ws = (char*)d_ws;
    unsigned short* xT   = (unsigned short*)(ws + OFF_XT);
    unsigned short* At2  = (unsigned short*)(ws + OFF_AT);
    unsigned int* pooled = (unsigned int*)(ws + OFF_POOLED);
    float* chsum  = (float*)(ws + OFF_CHSUM);
    float* chsq   = (float*)(ws + OFF_CHSQ);
    float* dynb   = (float*)(ws + OFF_DYNB);
    unsigned short* ybf  = (unsigned short*)(ws + OFF_Y);

    const bool bf16y = (ws_size >= (size_t)WS_NEED_BF16Y);

    // zero pooled (monotonic-enc) + chsum + chsq in one shot
    hipMemsetAsync(ws + OFF_POOLED, 0, 2560, stream);

    xpose_kernel<<<dim3(H_, T_, B_), 256, 0, stream>>>(x, xT, pooled);
    awgen_kernel<<<256, 256, 0, stream>>>(weights, pooled, W1, b1, W2, b2,
                                          biases, epochs, dynb, At2);
    if (bf16y) {
        conv_kernel<1><<<1792, 256, 0, stream>>>(xT, At2, dynb, out, ybf);
        stats_bf16_kernel<<<B_ * DIMS, 256, 0, stream>>>(ybf, chsum, chsq);
        norm_bf16_kernel<<<2048, 256, 0, stream>>>(ybf, chsum, chsq, gamma, beta, out);
    } else {
        conv_kernel<0><<<1792, 256, 0, stream>>>(xT, At2, dynb, out, nullptr);
        stats_f32_kernel<<<B_ * DIMS, 256, 0, stream>>>(out, chsum, chsq);
        norm_f32_kernel<<<2048, 256, 0, stream>>>(out, chsum, chsq, gamma, beta);
    }
}

// Round 21
// 196.528 us; speedup vs baseline: 1.1872x; 1.1200x over previous
//
#include <hip/hip_runtime.h>
#include <hip/hip_bf16.h>

// ---------- constants ----------
#define B_   8
#define CIN  64
#define DIMS 64
#define NW   8
#define T_   16
#define H_   56
#define W_   56
#define HID  17
#define THW  (T_*H_*W_)          // 50176
#define HW   (H_*W_)             // 3136
#define NPC  401408              // B*T*H*W per channel
#define EPS  1e-5f
#define PROWS 348                // 6 h-rows * 58 w-cols per LDS slice

typedef __bf16 bf16x8 __attribute__((ext_vector_type(8)));
typedef float f32x4 __attribute__((ext_vector_type(4)));

// workspace offsets (bytes)
#define OFF_XT     0             // xT bf16 = 51,380,224 B
#define OFF_AT     51380224      // At2 = 1,769,472 B
#define OFF_POOLED 53149696      // 512 u32
#define OFF_CHSUM  53151744
#define OFF_CHSQ   53152000
#define OFF_DYNB   53152512
#define OFF_Y      53155072      // optional bf16 y = 51,380,224 B (needs big ws)
#define WS_NEED_BF16Y (OFF_Y + 51380224)

__device__ __forceinline__ unsigned short f2bf(float f) {
    unsigned int u = __float_as_uint(f);
    u += 0x7fffu + ((u >> 16) & 1u);         // RNE (finite values)
    return (unsigned short)(u >> 16);
}
__device__ __forceinline__ float bf2f(unsigned short u) {
    return __uint_as_float(((unsigned int)u) << 16);
}
__device__ __forceinline__ unsigned int fenc(float f) {
    unsigned int b = __float_as_uint(f);
    return (b & 0x80000000u) ? ~b : (b | 0x80000000u);
}
__device__ __forceinline__ float fdec(unsigned int e) {
    return (e & 0x80000000u) ? __uint_as_float(e & 0x7fffffffu) : __uint_as_float(~e);
}

__device__ __forceinline__ float waveRedSum(float v) {
    #pragma unroll
    for (int o = 32; o > 0; o >>= 1) v += __shfl_down(v, o);
    return v;
}

// ---------- K0: transpose x -> xT bf16 + fused max pool, XCD batch-affine ----------
// 1D grid 7168 = 8 XCD-chunks x 896; XCD k owns batch k (matches conv).
__global__ __launch_bounds__(256) void xpose_kernel(const float* __restrict__ x,
                                                    unsigned short* __restrict__ xT,
                                                    unsigned int* __restrict__ pooled_u) {
    __shared__ float tile[CIN * W_];         // 14,336 B
    const int swz = (blockIdx.x & 7) * 896 + (blockIdx.x >> 3);
    const int b = swz / 896;
    const int rem = swz - b * 896;
    const int t = rem / 56, h = rem - t * 56;
    const int tid = threadIdx.x;
    {   // read: lane = w (coalesced 224B per c-row)
        const int w = tid & 63, cg = tid >> 6;
        if (w < W_) {
            const size_t base = ((size_t)(b * CIN) * T_ + t) * HW + h * W_ + w;
            #pragma unroll
            for (int k = 0; k < 16; ++k) {
                const int c = cg * 16 + k;
                tile[c * W_ + w] = x[base + (size_t)c * (T_ * HW)];
            }
        }
    }
    __syncthreads();
    {   // write: 32B per thread, fully coalesced
        const int w = tid >> 2, cq = tid & 3;
        if (w < W_) {
            unsigned int pk[8];
            #pragma unroll
            for (int kk = 0; kk < 8; ++kk) {
                const float f0 = tile[(cq * 16 + kk * 2) * W_ + w];
                const float f1 = tile[(cq * 16 + kk * 2 + 1) * W_ + w];
                pk[kk] = (unsigned int)f2bf(f0) | ((unsigned int)f2bf(f1) << 16);
            }
            unsigned short* dst = xT + ((((size_t)b * T_ + t) * H_ + h) * W_ + w) * CIN + cq * 16;
            *reinterpret_cast<uint4*>(dst)     = make_uint4(pk[0], pk[1], pk[2], pk[3]);
            *reinterpret_cast<uint4*>(dst + 8) = make_uint4(pk[4], pk[5], pk[6], pk[7]);
        }
    }
    if (tid < CIN) {
        float m = -3.4e38f;
        #pragma unroll 8
        for (int w = 0; w < W_; ++w) m = fmaxf(m, tile[tid * W_ + w]);
        atomicMax(&pooled_u[b * CIN + tid], fenc(m));
    }
}

// ---------- K3: At2 synth + inline MLP/softmax, XCD batch-affine ----------
// 1D grid 256 = 8 x 32; XCD k owns batch k (At2[b] stays L2-local for conv).
__global__ __launch_bounds__(256) void awgen_kernel(const float* __restrict__ weights,
                                                    const unsigned int* __restrict__ pooled_u,
                                                    const float* __restrict__ W1,
                                                    const float* __restrict__ b1,
                                                    const float* __restrict__ W2,
                                                    const float* __restrict__ b2,
                                                    const float* __restrict__ biases,
                                                    const void* __restrict__ epochs,
                                                    float* __restrict__ dynb,
                                                    unsigned short* __restrict__ At2) {
    const int swz = (blockIdx.x & 7) * 32 + (blockIdx.x >> 3);
    const int b = swz >> 5, oc = swz & 31;
    const int o0 = oc * 2;
    __shared__ float ph[NW];
    __shared__ float h_s[HID];
    const int tid = threadIdx.x;
    if (tid < HID) {
        float acc = b1[tid];
        #pragma unroll
        for (int c = 0; c < CIN; ++c) acc += fdec(pooled_u[b * CIN + c]) * W1[tid * CIN + c];
        h_s[tid] = fmaxf(acc, 0.0f);
    }
    __syncthreads();
    if (tid < NW) {
        float acc = b2[tid];
        #pragma unroll
        for (int j = 0; j < HID; ++j) acc += h_s[j] * W2[tid * HID + j];
        ph[tid] = acc;                       // logits
    }
    __syncthreads();
    if (tid == 0) {
        int e = ((const int*)epochs)[0];
        if (e < 0 || e > 1000000) e = (int)(((const float*)epochs)[0]);
        const float tau = (e < 10) ? (30.0f - 2.9f * (float)e) : 1.0f;
        float mx = -3.4e38f;
        #pragma unroll
        for (int n = 0; n < NW; ++n) mx = fmaxf(mx, ph[n]);
        float ex[NW], s = 0.0f;
        #pragma unroll
        for (int n = 0; n < NW; ++n) { ex[n] = expf((ph[n] - mx) / tau); s += ex[n]; }
        const bool ok = (s >= 1.0f) && (s < 1e37f);
        const float inv = ok ? (1.0f / s) : 0.0f;
        #pragma unroll
        for (int n = 0; n < NW; ++n) ph[n] = ok ? (ex[n] * inv) : 0.125f;
    }
    __syncthreads();
    if (oc == 0 && tid < DIMS) {             // 8 blocks write dynb
        float a = 0.0f;
        #pragma unroll
        for (int n = 0; n < NW; ++n) a += ph[n] * biases[n * DIMS + tid];
        dynb[b * DIMS + tid] = a;
    }
    const float4* w4 = reinterpret_cast<const float4*>(weights);
    for (int j = tid; j < 864; j += 256) {
        f32x4 a = (f32x4){0.f, 0.f, 0.f, 0.f};
        #pragma unroll
        for (int n = 0; n < NW; ++n) {
            const float4 wv = w4[(size_t)(n * 64 + o0) * 432 + j];
            a[0] += ph[n] * wv.x;
            a[1] += ph[n] * wv.y;
            a[2] += ph[n] * wv.z;
            a[3] += ph[n] * wv.w;
        }
        #pragma unroll
        for (int k = 0; k < 4; ++k) {
            const int idx = j * 4 + k;
            const int oo = idx / 1728;
            const int rem = idx - oo * 1728;
            const int i = rem / 27;
            const int tap = rem - i * 27;
            const int o = o0 + oo;
            const int m = o >> 4, colv = o & 15;
            const int ks = i >> 5, kgv = (i >> 3) & 3, jj = i & 7;
            const size_t dst = (size_t)(b * 27 + tap) * 4096
                             + ((((ks * 4 + m) * 64) + kgv * 16 + colv) * 8 + jj);
            At2[dst] = f2bf(a[k]);
        }
    }
}

// ---------- K4: MFMA conv — XCD swizzle + per-MFMA-cluster setprio (r17) ----------
// Session optimum: 114.5 µs, MfmaUtil 37%. Setprio stays TIGHT around each
// 32-MFMA cluster (r18: widening it nullifies the +22%).
template<int BF16Y>
__global__ __launch_bounds__(256) void conv_kernel(const unsigned short* __restrict__ xT,
                                                   const unsigned short* __restrict__ At2,
                                                   const float* __restrict__ dynb,
                                                   float* __restrict__ yf,
                                                   unsigned short* __restrict__ yb) {
    __shared__ __align__(16) unsigned char xs[PROWS * 128];   // 44,544 B
    const int swz = (blockIdx.x & 7) * 224 + (blockIdx.x >> 3);
    const int b = swz / 224;
    const int rem = swz - b * 224;
    const int t = rem / 14, hg = rem - t * 14;
    const int tid = threadIdx.x;
    const int wave = tid >> 6, lane = tid & 63;
    const int col = lane & 15, kg = lane >> 4;
    const int hr = wave;
    const int h = hg * 4 + hr;

    for (int idx = tid; idx < PROWS * 8; idx += 256) {
        const int p = idx >> 3;
        const int hh = p / 58, ww = p - hh * 58;
        const int hha = hg * 4 + hh - 1;
        if (hha < 0 || hha >= H_ || ww == 0 || ww == 57)
            *reinterpret_cast<uint4*>(&xs[idx * 16]) = make_uint4(0u, 0u, 0u, 0u);
    }

    f32x4 acc[4][4];
    #pragma unroll
    for (int m = 0; m < 4; ++m)
        #pragma unroll
        for (int n = 0; n < 4; ++n) acc[m][n] = (f32x4){0.f, 0.f, 0.f, 0.f};

    const int sub = lane >> 3, q = lane & 7;

    for (int kd = 0; kd < 3; ++kd) {
        const int td = t + kd - 1;
        if (td < 0 || td >= T_) continue;    // block-uniform skip
        __syncthreads();
        for (int item = wave; item < 42; item += 4) {
            const int hh = item / 7, qv = item - hh * 7;
            const int hha = hg * 4 + hh - 1;
            if (hha < 0 || hha >= H_) continue;
            const int p0 = hh * 58 + 1 + qv * 8;
            const int p = p0 + sub;
            const int w = qv * 8 + sub;
            const int qq = q ^ (p & 7);      // inverse-swizzled source (rule 21)
            const unsigned short* src = xT
                + ((((size_t)b * T_ + td) * H_ + hha) * W_ + w) * CIN + qq * 8;
            __builtin_amdgcn_global_load_lds(
                (const __attribute__((address_space(1))) unsigned int*)(const void*)src,
                (__attribute__((address_space(3))) unsigned int*)(void*)&xs[p0 * 128],
                16, 0, 0);
        }
        asm volatile("s_waitcnt vmcnt(0)" ::: "memory");
        __syncthreads();
        #pragma unroll
        for (int kh = 0; kh < 3; ++kh) {
            #pragma unroll
            for (int kw = 0; kw < 3; ++kw) {
                const int tap = kd * 9 + kh * 3 + kw;
                const unsigned short* ap = At2 + (size_t)(b * 27 + tap) * 4096;
                bf16x8 afr[4][2], bfr[4][2];
                #pragma unroll
                for (int ks = 0; ks < 2; ++ks)
                    #pragma unroll
                    for (int m = 0; m < 4; ++m)
                        afr[m][ks] = *reinterpret_cast<const bf16x8*>(
                            ap + (((ks * 4 + m) * 64) + lane) * 8);
                #pragma unroll
                for (int n = 0; n < 4; ++n) {
                    int ww = n * 16 + col + kw;
                    if (ww > 57) ww = 57;
                    const int p = (hr + kh) * 58 + ww;
                    #pragma unroll
                    for (int ks = 0; ks < 2; ++ks) {
                        const int slot = (ks * 4 + kg) ^ (p & 7);
                        bfr[n][ks] = *reinterpret_cast<const bf16x8*>(&xs[p * 128 + slot * 16]);
                    }
                }
                __builtin_amdgcn_s_setprio(1);
                #pragma unroll
                for (int ks = 0; ks < 2; ++ks)
                    #pragma unroll
                    for (int m = 0; m < 4; ++m)
                        #pragma unroll
                        for (int n = 0; n < 4; ++n)
                            acc[m][n] = __builtin_amdgcn_mfma_f32_16x16x32_bf16(
                                afr[m][ks], bfr[n][ks], acc[m][n], 0, 0, 0);
                __builtin_amdgcn_s_setprio(0);
            }
        }
    }

    #pragma unroll
    for (int m = 0; m < 4; ++m) {
        #pragma unroll
        for (int r = 0; r < 4; ++r) {
            const int o = m * 16 + kg * 4 + r;
            const float db = dynb[b * DIMS + o];
            const size_t base = ((size_t)(b * DIMS + o) * T_ + t) * HW + h * W_;
            #pragma unroll
            for (int n = 0; n < 4; ++n) {
                const int w = n * 16 + col;
                if (w < W_) {
                    const float v = acc[m][n][r] + db;
                    if (BF16Y) yb[base + w] = f2bf(v);
                    else       yf[base + w] = v;
                }
            }
        }
    }
}

// ---------- K5a: stats from f32 y, XCD batch-affine (512 = 8 x 64) ----------
__global__ __launch_bounds__(256) void stats_f32_kernel(const float* __restrict__ y,
                                                        float* __restrict__ chsum,
                                                        float* __restrict__ chsq) {
    const int bo = (blockIdx.x & 7) * 64 + (blockIdx.x >> 3);
    const int o = bo & 63;
    const float4* src = reinterpret_cast<const float4*>(y + (size_t)bo * THW);
    float s = 0.0f, qq = 0.0f;
    for (int idx = threadIdx.x; idx < THW / 4; idx += 256) {
        float4 v = src[idx];
        s += v.x + v.y + v.z + v.w;
        qq += v.x * v.x + v.y * v.y + v.z * v.z + v.w * v.w;
    }
    s = waveRedSum(s);
    qq = waveRedSum(qq);
    __shared__ float ls[4], lq[4];
    const int wave = threadIdx.x >> 6, lane = threadIdx.x & 63;
    if (lane == 0) { ls[wave] = s; lq[wave] = qq; }
    __syncthreads();
    if (threadIdx.x == 0) {
        atomicAdd(&chsum[o], ls[0] + ls[1] + ls[2] + ls[3]);
        atomicAdd(&chsq[o],  lq[0] + lq[1] + lq[2] + lq[3]);
    }
}

// ---------- K5b: stats from bf16 y, XCD batch-affine ----------
__global__ __launch_bounds__(256) void stats_bf16_kernel(const unsigned short* __restrict__ yb,
                                                         float* __restrict__ chsum,
                                                         float* __restrict__ chsq) {
    const int bo = (blockIdx.x & 7) * 64 + (blockIdx.x >> 3);
    const int o = bo & 63;
    const uint4* src = reinterpret_cast<const uint4*>(yb + (size_t)bo * THW);
    float s = 0.0f, qq = 0.0f;
    for (int idx = threadIdx.x; idx < THW / 8; idx += 256) {
        uint4 v = src[idx];
        unsigned int vv[4] = {v.x, v.y, v.z, v.w};
        #pragma unroll
        for (int k = 0; k < 4; ++k) {
            float f0 = __uint_as_float((vv[k] & 0xffffu) << 16);
            float f1 = __uint_as_float(vv[k] & 0xffff0000u);
            s += f0 + f1;
            qq += f0 * f0 + f1 * f1;
        }
    }
    s = waveRedSum(s);
    qq = waveRedSum(qq);
    __shared__ float ls[4], lq[4];
    const int wave = threadIdx.x >> 6, lane = threadIdx.x & 63;
    if (lane == 0) { ls[wave] = s; lq[wave] = qq; }
    __syncthreads();
    if (threadIdx.x == 0) {
        atomicAdd(&chsum[o], ls[0] + ls[1] + ls[2] + ls[3]);
        atomicAdd(&chsq[o],  lq[0] + lq[1] + lq[2] + lq[3]);
    }
}

// ---------- K7a: normalize+ReLU in place (f32), fin fused, XCD batch-affine ----------
__global__ __launch_bounds__(256) void norm_f32_kernel(float* __restrict__ y,
                                                       const float* __restrict__ chsum,
                                                       const float* __restrict__ chsq,
                                                       const float* __restrict__ gamma,
                                                       const float* __restrict__ beta) {
    const int swz = (blockIdx.x & 7) * 256 + (blockIdx.x >> 3);
    const int bo = swz >> 2, qq = swz & 3;
    const int o = bo & 63;
    const float inv = 1.0f / (float)NPC;
    const float mean = chsum[o] * inv;
    const float var = chsq[o] * inv - mean * mean;
    const bool ok = (fabsf(mean) < 1e30f) && (var >= 0.0f) && (var < 1e30f);
    const float rstd = ok ? rsqrtf(var + EPS) : 0.0f;
    const float s = gamma[o] * rstd;
    const float sh = ok ? (beta[o] - mean * s) : 0.69f;
    float4* buf = reinterpret_cast<float4*>(y + (size_t)bo * THW) + qq * (THW / 16);
    for (int idx = threadIdx.x; idx < THW / 16; idx += 256) {
        float4 v = buf[idx];
        v.x = fmaxf(v.x * s + sh, 0.0f);
        v.y = fmaxf(v.y * s + sh, 0.0f);
        v.z = fmaxf(v.z * s + sh, 0.0f);
        v.w = fmaxf(v.w * s + sh, 0.0f);
        buf[idx] = v;
    }
}

// ---------- K7b: normalize+ReLU bf16 y -> f32 out, fin fused, XCD batch-affine ----------
__global__ __launch_bounds__(256) void norm_bf16_kernel(const unsigned short* __restrict__ yb,
                                                        const float* __restrict__ chsum,
                                                        const float* __restrict__ chsq,
                                                        const float* __restrict__ gamma,
                                                        const float* __restrict__ beta,
                                                        float* __restrict__ out) {
    const int swz = (blockIdx.x & 7) * 256 + (blockIdx.x >> 3);
    const int bo = swz >> 2, qq = swz & 3;
    const int o = bo & 63;
    const float inv = 1.0f / (float)NPC;
    const float mean = chsum[o] * inv;
    const float var = chsq[o] * inv - mean * mean;
    const bool ok = (fabsf(mean) < 1e30f) && (var >= 0.0f) && (var < 1e30f);
    const float rstd = ok ? rsqrtf(var + EPS) : 0.0f;
    const float s = gamma[o] * rstd;
    const float sh = ok ? (beta[o] - mean * s) : 0.69f;
    const uint4* src = reinterpret_cast<const uint4*>(yb + (size_t)bo * THW) + qq * (THW / 32);
    float4* dst = reinterpret_cast<float4*>(out + (size_t)bo * THW) + qq * (THW / 16);
    for (int idx = threadIdx.x; idx < THW / 32; idx += 256) {
        uint4 v = src[idx];
        unsigned int vv[4] = {v.x, v.y, v.z, v.w};
        float4 r0, r1;
        float* rp[2] = {&r0.x, &r1.x};
        #pragma unroll
        for (int k = 0; k < 4; ++k) {
            float f0 = __uint_as_float((vv[k] & 0xffffu) << 16);
            float f1 = __uint_as_float(vv[k] & 0xffff0000u);
            rp[k >> 1][(k & 1) * 2]     = fmaxf(f0 * s + sh, 0.0f);
            rp[k >> 1][(k & 1) * 2 + 1] = fmaxf(f1 * s + sh, 0.0f);
        }
        dst[idx * 2]     = r0;
        dst[idx * 2 + 1] = r1;
    }
}

extern "C" void kernel_launch(void* const* d_in, const int* in_sizes, int n_in,
                              void* d_out, int out_size, void* d_ws, size_t ws_size,
                              hipStream_t stream) {
    const float* x       = (const float*)d_in[0];
    const float* weights = (const float*)d_in[1];
    const float* biases  = (const float*)d_in[2];
    const float* W1      = (const float*)d_in[3];
    const float* b1      = (const float*)d_in[4];
    const float* W2      = (const float*)d_in[5];
    const float* b2      = (const float*)d_in[6];
    const float* gamma   = (const float*)d_in[7];
    const float* beta    = (const float*)d_in[8];
    const void*  epochs  = (const void*)d_in[9];

    float* out = (float*)d_out;
    char* ws = (char*)d_ws;
    unsigned short* xT   = (unsigned short*)(ws + OFF_XT);
    unsigned short* At2  = (unsigned short*)(ws + OFF_AT);
    unsigned int* pooled = (unsigned int*)(ws + OFF_POOLED);
    float* chsum  = (float*)(ws + OFF_CHSUM);
    float* chsq   = (float*)(ws + OFF_CHSQ);
    float* dynb   = (float*)(ws + OFF_DYNB);
    unsigned short* ybf  = (unsigned short*)(ws + OFF_Y);

    const bool bf16y = (ws_size >= (size_t)WS_NEED_BF16Y);

    // zero pooled (monotonic-enc) + chsum + chsq in one shot
    hipMemsetAsync(ws + OFF_POOLED, 0, 2560, stream);

    xpose_kernel<<<7168, 256, 0, stream>>>(x, xT, pooled);
    awgen_kernel<<<256, 256, 0, stream>>>(weights, pooled, W1, b1, W2, b2,
                                          biases, epochs, dynb, At2);
    if (bf16y) {
        conv_kernel<1><<<1792, 256, 0, stream>>>(xT, At2, dynb, out, ybf);
        stats_bf16_kernel<<<512, 256, 0, stream>>>(ybf, chsum, chsq);
        norm_bf16_kernel<<<2048, 256, 0, stream>>>(ybf, chsum, chsq, gamma, beta, out);
    } else {
        conv_kernel<0><<<1792, 256, 0, stream>>>(xT, At2, dynb, out, nullptr);
        stats_f32_kernel<<<512, 256, 0, stream>>>(out, chsum, chsq);
        norm_f32_kernel<<<2048, 256, 0, stream>>>(out, chsum, chsq, gamma, beta);
    }
}